// Round 2
// baseline (1544.296 us; speedup 1.0000x reference)
//
#include <hip/hip_runtime.h>
#include <stdint.h>
#include <stddef.h>

// Conv_M: fused dynamic-filter conv. B=4, Cin=Cout=64, H=W=128, K=3.
// Pipeline: k_feat (patches->bf16, MFMA-friendly layout) ; k_sw (W1/W2 -> bf16
// swizzled B-frag order) ; k_gemm1 (feat@W1 -> yr/mr/sr) ; k_gemm2
// (feat@W2 fused epilogue -> y, m_y/s_y, ones).
// All GEMMs: v_mfma_f32_16x16x32_bf16, A/B staged via global_load_lds(16B).
//
// R1 bug (absmax 24.4 ~= half-channel partial): k_gemm2 split channels across
// wn=wv&1 wave pairs but stored without merging -> one wave overwrote the
// other's half-sum. R2 adds an LDS cross-wave reduction before the store.

using short8  = __attribute__((ext_vector_type(8))) short;
using float4v = __attribute__((ext_vector_type(4))) float;

#define DI __device__ __forceinline__

DI unsigned short f2bf(float f) {
  union { float f; unsigned int u; } a; a.f = f;
  unsigned int r = a.u + 0x7fffu + ((a.u >> 16) & 1u);
  return (unsigned short)(r >> 16);
}
DI float bf2f(unsigned short u) {
  union { unsigned int u; float f; } a; a.u = ((unsigned int)u) << 16;
  return a.f;
}
DI void gll16(const void* g, void* l) {
  __builtin_amdgcn_global_load_lds(
      (const __attribute__((address_space(1))) unsigned int*)g,
      (__attribute__((address_space(3))) unsigned int*)l, 16, 0, 0);
}

// ---------------------------------------------------------------------------
// feat layout: idx = ((kk*512 + pblk)*4 + q)*1024 + plocal*8 + j8
//   kk = k/32 (36 blocks), pblk = pixel/128 (512), q = (k>>3)&3, j8 = k&7.
// feat col = c*9 + (kh*3+kw) for x (cols 0..575), same +576 for m.
// ---------------------------------------------------------------------------
__global__ void k_feat(const float* __restrict__ x, const float* __restrict__ m,
                       unsigned short* __restrict__ featb) {
  unsigned int tid = blockIdx.x * 256u + threadIdx.x;  // < 75,497,472
  int j8   = tid & 7;
  int pl   = (tid >> 3) & 127;
  int q    = (tid >> 10) & 3;
  int pblk = (tid >> 12) & 511;
  int kk   = tid >> 21;
  int col  = kk * 32 + q * 8 + j8;
  const float* src = x;
  int jx = col;
  if (col >= 576) { src = m; jx = col - 576; }
  int c  = jx / 9;
  int t  = jx - c * 9;
  int t3 = t / 3;
  int dh = t3 - 1;
  int dw = (t - t3 * 3) - 1;
  int p  = pblk * 128 + pl;
  int b  = p >> 14, h = (p >> 7) & 127, w = p & 127;
  int hh = min(max(h + dh, 0), 127);   // replicate pad
  int ww = min(max(w + dw, 0), 127);
  featb[tid] = f2bf(src[(((b << 6) | c) << 14) + (hh << 7) + ww]);
}

// Weight swizzle: src row-major [k][n] fp32 -> bf16 at
//   idx = ((k>>5)*ntiles + (n>>4))*512 + ((k>>3)&3)*128 + (n&15)*8 + (k&7)
__global__ void k_sw(const float* __restrict__ Wsrc, unsigned short* __restrict__ Wdst,
                     int ncols, int ntiles, int total) {
  int tid = blockIdx.x * 256 + threadIdx.x;
  if (tid >= total) return;
  int k = tid / ncols;
  int n = tid - k * ncols;
  int out = ((k >> 5) * ntiles + (n >> 4)) * 512 + ((k >> 3) & 3) * 128 +
            (n & 15) * 8 + (k & 7);
  Wdst[out] = f2bf(Wsrc[tid]);
}

// ---------------------------------------------------------------------------
// GEMM1: w1 = feat@W1 + b1, then yr/mr/sr[p][c] via 3x3 taps on fp32 x/m/s.
// Each wave owns 16 full rows x all 144 cols -> no cross-wave channel split.
// ---------------------------------------------------------------------------
__launch_bounds__(512, 2)
__global__ void k_gemm1(const unsigned short* __restrict__ featb,
                        const unsigned short* __restrict__ W1s,
                        const float* __restrict__ b1,
                        const float* __restrict__ x, const float* __restrict__ m,
                        const float* __restrict__ s,
                        float* __restrict__ yr, float* __restrict__ mr,
                        float* __restrict__ sr) {
  __shared__ __align__(16) unsigned short Alds[4096];       // 8KB  [q][p128][j8]
  __shared__ __align__(16) unsigned short Blds[4608];       // 9216B: 9 tiles
  __shared__ __align__(16) unsigned short w1buf[128 * 152]; // 38912B
  const int tid = threadIdx.x;
  const int wv  = tid >> 6;
  const int l15 = tid & 15;
  const int q   = (tid >> 4) & 3;
  const int bm  = blockIdx.x, nb = blockIdx.y;

  float4v acc[9];
#pragma unroll
  for (int t = 0; t < 9; ++t) acc[t] = (float4v){0.f, 0.f, 0.f, 0.f};

  const unsigned short* Ab = featb + (size_t)bm * 4096;
  const unsigned short* Bb = W1s + (size_t)nb * 9 * 512;

  for (int kk = 0; kk < 36; ++kk) {
    __syncthreads();
    gll16(Ab + (size_t)kk * 2097152 + tid * 8, (char*)Alds + wv * 1024);
    gll16(Bb + (size_t)kk * 18432 + tid * 8, (char*)Blds + wv * 1024);
    if (tid < 64) gll16(Bb + (size_t)kk * 18432 + 4096 + tid * 8, (char*)Blds + 8192);
    __syncthreads();
    short8 af = *(const short8*)&Alds[q * 1024 + (16 * wv + l15) * 8];
#pragma unroll
    for (int t = 0; t < 9; ++t) {
      short8 bfr = *(const short8*)&Blds[t * 512 + q * 128 + l15 * 8];
      acc[t] = __builtin_amdgcn_mfma_f32_16x16x32_bf16(af, bfr, acc[t], 0, 0, 0);
    }
  }

  // w1 (+bias) -> LDS as bf16. C/D layout: col=lane&15, row=quad*4+i.
#pragma unroll
  for (int t = 0; t < 9; ++t) {
    int col = 16 * t + l15;
    float bb = b1[nb * 144 + col];
#pragma unroll
    for (int i = 0; i < 4; ++i) {
      int plr = 16 * wv + 4 * q + i;
      w1buf[plr * 152 + col] = f2bf(acc[t][i] + bb);
    }
  }
  __syncthreads();

  const int b = bm >> 7, h = bm & 127;  // m-block = one (b,h) image row
#pragma unroll
  for (int ii = 0; ii < 4; ++ii) {
    int task = ii * 512 + tid;     // 2048 tasks: (p 0..127) x (cl 0..15)
    int p  = task >> 4;
    int cl = task & 15;
    int c  = nb * 16 + cl;
    float w1v[9];
#pragma unroll
    for (int k = 0; k < 9; ++k) w1v[k] = bf2f(w1buf[p * 152 + cl * 9 + k]);
    size_t base = (size_t)(((b << 6) | c) << 14);
    float vy = 0.f, vm = 0.f, vs = 0.f;
#pragma unroll
    for (int dh = -1; dh <= 1; ++dh) {
      int hh = min(max(h + dh, 0), 127);
#pragma unroll
      for (int dw = -1; dw <= 1; ++dw) {
        int ww = min(max(p + dw, 0), 127);
        size_t idx = base + (hh << 7) + ww;
        int k = (dh + 1) * 3 + (dw + 1);
        float wv1 = w1v[k], aw = fabsf(wv1);
        vy += x[idx] * wv1;
        vm += m[idx] * aw;
        vs += s[idx] * aw;
      }
    }
    size_t P = (size_t)bm * 128 + p;
    yr[P * 64 + c] = vy;
    mr[P * 64 + c] = vm;
    sr[P * 64 + c] = vs;
  }
}

// ---------------------------------------------------------------------------
// GEMM2: w2 = feat@W2 + b2 streamed in 16 chunks of 256 cols (4 channels);
// per-chunk epilogue contracts with yr/mr/sr into persistent registers.
// Waves: wm=wv>>1 picks 32-row group, wn=wv&1 picks 128-col half.
// wn=0 holds channels c%4 in {0,1}, wn=1 holds {2,3} -> merge via LDS at end.
// ---------------------------------------------------------------------------
__launch_bounds__(512, 2)
__global__ void k_gemm2(const unsigned short* __restrict__ featb,
                        const unsigned short* __restrict__ W2s,
                        const float* __restrict__ b2,
                        const float* __restrict__ yr, const float* __restrict__ mr,
                        const float* __restrict__ sr,
                        float* __restrict__ out) {
  __shared__ __align__(16) unsigned short Alds[4096];  // 8KB
  __shared__ __align__(16) unsigned short Blds[8192];  // 16KB: 16 tiles
  __shared__ float red[4][32][64];                     // 32KB merge buffer
  const int tid  = threadIdx.x;
  const int wv   = tid >> 6;
  const int lane = tid & 63;
  const int wm   = wv >> 1;      // 0..3: row group of 32
  const int wn   = wv & 1;       // 0..1: col group of 128
  const int l15  = tid & 15;
  const int q    = (tid >> 4) & 3;
  const int bm   = blockIdx.x;

  float yp_[2][4][4] = {}, mp_[2][4][4] = {}, sp_[2][4][4] = {};
  const unsigned short* Ab = featb + (size_t)bm * 4096;

  for (int ch = 0; ch < 16; ++ch) {
    float4v acc[2][8];
#pragma unroll
    for (int tm = 0; tm < 2; ++tm)
#pragma unroll
      for (int t = 0; t < 8; ++t) acc[tm][t] = (float4v){0.f, 0.f, 0.f, 0.f};

    const unsigned short* Bb = W2s + (size_t)ch * 8192;

    for (int kk = 0; kk < 36; ++kk) {
      __syncthreads();
      gll16(Ab + (size_t)kk * 2097152 + tid * 8, (char*)Alds + wv * 1024);
      gll16(Bb + (size_t)kk * 131072 + tid * 8, (char*)Blds + wv * 1024);
      gll16(Bb + (size_t)kk * 131072 + 4096 + tid * 8,
            (char*)Blds + 8192 + wv * 1024);
      __syncthreads();
      short8 a0 = *(const short8*)&Alds[q * 1024 + (32 * wm + l15) * 8];
      short8 a1 = *(const short8*)&Alds[q * 1024 + (32 * wm + 16 + l15) * 8];
#pragma unroll
      for (int t = 0; t < 8; ++t) {
        short8 bfr = *(const short8*)&Blds[(8 * wn + t) * 512 + q * 128 + l15 * 8];
        acc[0][t] = __builtin_amdgcn_mfma_f32_16x16x32_bf16(a0, bfr, acc[0][t], 0, 0, 0);
        acc[1][t] = __builtin_amdgcn_mfma_f32_16x16x32_bf16(a1, bfr, acc[1][t], 0, 0, 0);
      }
    }

    // epilogue: n_global = ch*256 + 128*wn + 16*t + l15 ; c = n>>6 ; o = n&63
    float b2v[8];
#pragma unroll
    for (int t = 0; t < 8; ++t) b2v[t] = b2[ch * 256 + 128 * wn + 16 * t + l15];
#pragma unroll
    for (int tq = 0; tq < 2; ++tq) {
      int c = ch * 4 + 2 * wn + tq;
#pragma unroll
      for (int tm = 0; tm < 2; ++tm) {
#pragma unroll
        for (int i = 0; i < 4; ++i) {
          size_t P = (size_t)bm * 128 + 32 * wm + 16 * tm + 4 * q + i;
          float yv = yr[P * 64 + c];
          float mv = mr[P * 64 + c];
          float sv = sr[P * 64 + c];
#pragma unroll
          for (int oq = 0; oq < 4; ++oq) {
            int t = tq * 4 + oq;
            float w2v = acc[tm][t][i] + b2v[t];
            float aw  = fabsf(w2v);
            yp_[tm][i][oq] += yv * w2v;
            mp_[tm][i][oq] += mv * aw;
            sp_[tm][i][oq] += sv * aw;
          }
        }
      }
    }
  }

  // ---- cross-wave merge: wn=1 partials -> wn=0 (same wm, same lane) ----
  __syncthreads();
#pragma unroll
  for (int tm = 0; tm < 2; ++tm)
#pragma unroll
    for (int i = 0; i < 4; ++i)
#pragma unroll
      for (int oq = 0; oq < 4; ++oq)
        if (wn == 1) red[wm][tm * 16 + i * 4 + oq][lane] = yp_[tm][i][oq];
  __syncthreads();
#pragma unroll
  for (int tm = 0; tm < 2; ++tm)
#pragma unroll
    for (int i = 0; i < 4; ++i)
#pragma unroll
      for (int oq = 0; oq < 4; ++oq)
        if (wn == 0) yp_[tm][i][oq] += red[wm][tm * 16 + i * 4 + oq][lane];
  __syncthreads();
#pragma unroll
  for (int tm = 0; tm < 2; ++tm)
#pragma unroll
    for (int i = 0; i < 4; ++i)
#pragma unroll
      for (int oq = 0; oq < 4; ++oq)
        if (wn == 1) red[wm][tm * 16 + i * 4 + oq][lane] = mp_[tm][i][oq];
  __syncthreads();
#pragma unroll
  for (int tm = 0; tm < 2; ++tm)
#pragma unroll
    for (int i = 0; i < 4; ++i)
#pragma unroll
      for (int oq = 0; oq < 4; ++oq)
        if (wn == 0) mp_[tm][i][oq] += red[wm][tm * 16 + i * 4 + oq][lane];
  __syncthreads();
#pragma unroll
  for (int tm = 0; tm < 2; ++tm)
#pragma unroll
    for (int i = 0; i < 4; ++i)
#pragma unroll
      for (int oq = 0; oq < 4; ++oq)
        if (wn == 1) red[wm][tm * 16 + i * 4 + oq][lane] = sp_[tm][i][oq];
  __syncthreads();
#pragma unroll
  for (int tm = 0; tm < 2; ++tm)
#pragma unroll
    for (int i = 0; i < 4; ++i)
#pragma unroll
      for (int oq = 0; oq < 4; ++oq)
        if (wn == 0) sp_[tm][i][oq] += red[wm][tm * 16 + i * 4 + oq][lane];

  // stores (wn==0 waves only): out0[b,o,h,w], out1 = m_y/s_y, out2 = 1
  if (wn == 0) {
    const int b = bm >> 7, h = bm & 127;
#pragma unroll
    for (int tm = 0; tm < 2; ++tm)
#pragma unroll
      for (int i = 0; i < 4; ++i)
#pragma unroll
        for (int oq = 0; oq < 4; ++oq) {
          int plr = 32 * wm + 16 * tm + 4 * q + i;
          int o   = 16 * oq + l15;
          size_t idx = ((size_t)((b << 6) | o) << 14) + (h << 7) + plr;
          out[idx]           = yp_[tm][i][oq];
          out[4194304 + idx] = mp_[tm][i][oq] / sp_[tm][i][oq];
          out[8388608 + idx] = 1.0f;
        }
  }
}

// ---------------------------------------------------------------------------
extern "C" void kernel_launch(void* const* d_in, const int* in_sizes, int n_in,
                              void* d_out, int out_size, void* d_ws, size_t ws_size,
                              hipStream_t stream) {
  const float* x  = (const float*)d_in[0];
  const float* m  = (const float*)d_in[1];
  const float* s  = (const float*)d_in[2];
  const float* W1 = (const float*)d_in[3];
  const float* b1 = (const float*)d_in[4];
  const float* W2 = (const float*)d_in[5];
  const float* b2 = (const float*)d_in[6];
  float* out = (float*)d_out;

  // ws layout (bytes):
  //   feat  bf16 : [0, 150994944)               36*65536*32 elems
  //   W1s   bf16 : [150994944, 152322048)       1152*576
  //   W2s   bf16 : [152322048, 161759232)       1152*4096
  //   yr/mr/sr f32: 3 x 16777216 from 161759232 ; end = 212090880
  if (ws_size < 212090880ull) return;  // (R1 evidence: ws is big enough - kernels ran)
  char* ws = (char*)d_ws;
  unsigned short* featb = (unsigned short*)ws;
  unsigned short* W1s   = (unsigned short*)(ws + 150994944);
  unsigned short* W2s   = (unsigned short*)(ws + 152322048);
  float* yr = (float*)(ws + 161759232);
  float* mr = (float*)(ws + 178536448);
  float* sr = (float*)(ws + 195313664);

  k_feat<<<294912, 256, 0, stream>>>(x, m, featb);
  k_sw<<<2592, 256, 0, stream>>>(W1, W1s, 576, 36, 663552);
  k_sw<<<18432, 256, 0, stream>>>(W2, W2s, 4096, 256, 4718592);
  dim3 g1(512, 4);
  k_gemm1<<<g1, 512, 0, stream>>>(featb, W1s, b1, x, m, s, yr, mr, sr);
  k_gemm2<<<512, 512, 0, stream>>>(featb, W2s, b2, yr, mr, sr, out);
}

// Round 3
// 1532.252 us; speedup vs baseline: 1.0079x; 1.0079x over previous
//
#include <hip/hip_runtime.h>
#include <stdint.h>
#include <stddef.h>

// Conv_M: fused dynamic-filter conv. B=4, Cin=Cout=64, H=W=128, K=3.
// R3: k_gemm2 rewritten — o-major W2 permute (chunk = 4 outch x all 64 c, so
// the c-contraction completes per chunk: no persistent partials, no merge),
// 64x128 wave tiles (LDS frag-read ceiling 53%->89%), double-buffered
// single-barrier K-loop, 256-thread blocks with 2 blocks/CU.

using short8  = __attribute__((ext_vector_type(8))) short;
using float4v = __attribute__((ext_vector_type(4))) float;

#define DI __device__ __forceinline__

DI unsigned short f2bf(float f) {
  union { float f; unsigned int u; } a; a.f = f;
  unsigned int r = a.u + 0x7fffu + ((a.u >> 16) & 1u);
  return (unsigned short)(r >> 16);
}
DI float bf2f(unsigned short u) {
  union { unsigned int u; float f; } a; a.u = ((unsigned int)u) << 16;
  return a.f;
}
DI void gll16(const void* g, void* l) {
  __builtin_amdgcn_global_load_lds(
      (const __attribute__((address_space(1))) unsigned int*)g,
      (__attribute__((address_space(3))) unsigned int*)l, 16, 0, 0);
}

// 16-lane (l15-group) sum via DPP — VALU pipe, no LDS traffic.
template <int CTRL>
DI float dpp_add(float v) {
  union { float f; int i; } a; a.f = v;
  a.i = __builtin_amdgcn_update_dpp(0, a.i, CTRL, 0xF, 0xF, true);
  return v + a.f;
}
DI float sum16(float v) {
  v = dpp_add<0xB1>(v);   // quad_perm [1,0,3,2]
  v = dpp_add<0x4E>(v);   // quad_perm [2,3,0,1]
  v = dpp_add<0x141>(v);  // row_half_mirror
  v = dpp_add<0x140>(v);  // row_mirror
  return v;
}

// ---------------------------------------------------------------------------
// feat layout: idx = ((kk*512 + pblk)*4 + q)*1024 + plocal*8 + j8
//   kk = k/32 (36 blocks), pblk = pixel/128 (512), q = (k>>3)&3, j8 = k&7.
// feat col = c*9 + (kh*3+kw) for x (cols 0..575), same +576 for m.
// ---------------------------------------------------------------------------
__global__ void k_feat(const float* __restrict__ x, const float* __restrict__ m,
                       unsigned short* __restrict__ featb) {
  unsigned int tid = blockIdx.x * 256u + threadIdx.x;  // < 75,497,472
  int j8   = tid & 7;
  int pl   = (tid >> 3) & 127;
  int q    = (tid >> 10) & 3;
  int pblk = (tid >> 12) & 511;
  int kk   = tid >> 21;
  int col  = kk * 32 + q * 8 + j8;
  const float* src = x;
  int jx = col;
  if (col >= 576) { src = m; jx = col - 576; }
  int c  = jx / 9;
  int t  = jx - c * 9;
  int t3 = t / 3;
  int dh = t3 - 1;
  int dw = (t - t3 * 3) - 1;
  int p  = pblk * 128 + pl;
  int b  = p >> 14, h = (p >> 7) & 127, w = p & 127;
  int hh = min(max(h + dh, 0), 127);   // replicate pad
  int ww = min(max(w + dw, 0), 127);
  featb[tid] = f2bf(src[(((b << 6) | c) << 14) + (hh << 7) + ww]);
}

// Weight swizzle: src row-major [k][n] fp32 -> bf16 B-frag tiles at
//   idx = ((k>>5)*ntiles + (n'>>4))*512 + ((k>>3)&3)*128 + (n'&15)*8 + (k&7)
// perm=1 (W2): n' = (n&63)<<6 | (n>>6)  (o-major: n' = o*64 + c).
__global__ void k_sw(const float* __restrict__ Wsrc, unsigned short* __restrict__ Wdst,
                     int ncols, int ntiles, int total, int perm) {
  int tid = blockIdx.x * 256 + threadIdx.x;
  if (tid >= total) return;
  int k = tid / ncols;
  int n = tid - k * ncols;
  int np = perm ? (((n & 63) << 6) | (n >> 6)) : n;
  int out = ((k >> 5) * ntiles + (np >> 4)) * 512 + ((k >> 3) & 3) * 128 +
            (np & 15) * 8 + (k & 7);
  Wdst[out] = f2bf(Wsrc[tid]);
}

// ---------------------------------------------------------------------------
// GEMM1: w1 = feat@W1 + b1, then yr/mr/sr[p][c] via 3x3 taps on fp32 x/m/s.
// ---------------------------------------------------------------------------
__launch_bounds__(512, 2)
__global__ void k_gemm1(const unsigned short* __restrict__ featb,
                        const unsigned short* __restrict__ W1s,
                        const float* __restrict__ b1,
                        const float* __restrict__ x, const float* __restrict__ m,
                        const float* __restrict__ s,
                        float* __restrict__ yr, float* __restrict__ mr,
                        float* __restrict__ sr) {
  __shared__ __align__(16) unsigned short Alds[4096];       // 8KB  [q][p128][j8]
  __shared__ __align__(16) unsigned short Blds[4608];       // 9216B: 9 tiles
  __shared__ __align__(16) unsigned short w1buf[128 * 152]; // 38912B
  const int tid = threadIdx.x;
  const int wv  = tid >> 6;
  const int l15 = tid & 15;
  const int q   = (tid >> 4) & 3;
  const int bm  = blockIdx.x, nb = blockIdx.y;

  float4v acc[9];
#pragma unroll
  for (int t = 0; t < 9; ++t) acc[t] = (float4v){0.f, 0.f, 0.f, 0.f};

  const unsigned short* Ab = featb + (size_t)bm * 4096;
  const unsigned short* Bb = W1s + (size_t)nb * 9 * 512;

  for (int kk = 0; kk < 36; ++kk) {
    __syncthreads();
    gll16(Ab + (size_t)kk * 2097152 + tid * 8, (char*)Alds + wv * 1024);
    gll16(Bb + (size_t)kk * 18432 + tid * 8, (char*)Blds + wv * 1024);
    if (tid < 64) gll16(Bb + (size_t)kk * 18432 + 4096 + tid * 8, (char*)Blds + 8192);
    __syncthreads();
    short8 af = *(const short8*)&Alds[q * 1024 + (16 * wv + l15) * 8];
#pragma unroll
    for (int t = 0; t < 9; ++t) {
      short8 bfr = *(const short8*)&Blds[t * 512 + q * 128 + l15 * 8];
      acc[t] = __builtin_amdgcn_mfma_f32_16x16x32_bf16(af, bfr, acc[t], 0, 0, 0);
    }
  }

  // w1 (+bias) -> LDS as bf16. C/D layout: col=lane&15, row=quad*4+i.
#pragma unroll
  for (int t = 0; t < 9; ++t) {
    int col = 16 * t + l15;
    float bb = b1[nb * 144 + col];
#pragma unroll
    for (int i = 0; i < 4; ++i) {
      int plr = 16 * wv + 4 * q + i;
      w1buf[plr * 152 + col] = f2bf(acc[t][i] + bb);
    }
  }
  __syncthreads();

  const int b = bm >> 7, h = bm & 127;  // m-block = one (b,h) image row
#pragma unroll
  for (int ii = 0; ii < 4; ++ii) {
    int task = ii * 512 + tid;     // 2048 tasks: (p 0..127) x (cl 0..15)
    int p  = task >> 4;
    int cl = task & 15;
    int c  = nb * 16 + cl;
    float w1v[9];
#pragma unroll
    for (int k = 0; k < 9; ++k) w1v[k] = bf2f(w1buf[p * 152 + cl * 9 + k]);
    size_t base = (size_t)(((b << 6) | c) << 14);
    float vy = 0.f, vm = 0.f, vs = 0.f;
#pragma unroll
    for (int dh = -1; dh <= 1; ++dh) {
      int hh = min(max(h + dh, 0), 127);
#pragma unroll
      for (int dw = -1; dw <= 1; ++dw) {
        int ww = min(max(p + dw, 0), 127);
        size_t idx = base + (hh << 7) + ww;
        int k = (dh + 1) * 3 + (dw + 1);
        float wv1 = w1v[k], aw = fabsf(wv1);
        vy += x[idx] * wv1;
        vm += m[idx] * aw;
        vs += s[idx] * aw;
      }
    }
    size_t P = (size_t)bm * 128 + p;
    yr[P * 64 + c] = vy;
    mr[P * 64 + c] = vm;
    sr[P * 64 + c] = vs;
  }
}

// ---------------------------------------------------------------------------
// GEMM2 (rewritten): block = 128 rows x 256 cols/chunk, 16 chunks (o-major:
// chunk ch covers o in {4ch..4ch+3}, all 64 c). 4 waves (wm row-group of 64,
// wn col-group of 128), wave tile 64x128, acc[4][8]. Double-buffered LDS,
// one barrier per K-step. Epilogue per chunk: w2=acc+b2, contract c in-lane
// (4 terms) then across the 16-lane group via DPP; lane l15==0 stores.
// ---------------------------------------------------------------------------
__launch_bounds__(256, 2)
__global__ void k_gemm2(const unsigned short* __restrict__ featb,
                        const unsigned short* __restrict__ W2s,
                        const float* __restrict__ b2,
                        const float* __restrict__ yr, const float* __restrict__ mr,
                        const float* __restrict__ sr,
                        float* __restrict__ out) {
  __shared__ __align__(16) unsigned short Alds[2][4096];  // 2 x 8KB
  __shared__ __align__(16) unsigned short Blds[2][8192];  // 2 x 16KB
  const int tid  = threadIdx.x;
  const int wv   = tid >> 6;
  const int wm   = wv >> 1;      // 0..1: 64-row group
  const int wn   = wv & 1;       // 0..1: 128-col group
  const int l15  = tid & 15;
  const int q    = (tid >> 4) & 3;
  const int bm   = blockIdx.x;
  const int b    = bm >> 7, h = bm & 127;

  const unsigned short* Ab = featb + (size_t)bm * 4096;

  float4v acc[4][8];
#pragma unroll
  for (int r = 0; r < 4; ++r)
#pragma unroll
    for (int t = 0; t < 8; ++t) acc[r][t] = (float4v){0.f, 0.f, 0.f, 0.f};

  // prologue: stage (ch=0, kk=0) into buffer 0
  {
    const unsigned short* Ag = Ab;
    const unsigned short* Bg = W2s;
#pragma unroll
    for (int rr = 0; rr < 2; ++rr)
      gll16(Ag + (rr * 256 + tid) * 8, (char*)Alds[0] + rr * 4096 + wv * 1024);
#pragma unroll
    for (int rr = 0; rr < 4; ++rr)
      gll16(Bg + (rr * 256 + tid) * 8, (char*)Blds[0] + rr * 4096 + wv * 1024);
  }

  for (int ch = 0; ch < 16; ++ch) {
    for (int kk = 0; kk < 36; ++kk) {
      __syncthreads();  // buf[kk&1] staged; prior reads of buf[(kk+1)&1] done
      if (!(ch == 15 && kk == 35)) {
        int kkn = (kk == 35) ? 0 : kk + 1;
        int chn = (kk == 35) ? ch + 1 : ch;
        const unsigned short* Ag = Ab + (size_t)kkn * 2097152;
        const unsigned short* Bg = W2s + (size_t)kkn * 131072 + chn * 8192;
        char* Al = (char*)Alds[(kk + 1) & 1];
        char* Bl = (char*)Blds[(kk + 1) & 1];
#pragma unroll
        for (int rr = 0; rr < 2; ++rr)
          gll16(Ag + (rr * 256 + tid) * 8, Al + rr * 4096 + wv * 1024);
#pragma unroll
        for (int rr = 0; rr < 4; ++rr)
          gll16(Bg + (rr * 256 + tid) * 8, Bl + rr * 4096 + wv * 1024);
      }
      const unsigned short* Al = Alds[kk & 1];
      const unsigned short* Bl = Blds[kk & 1];
      short8 a[4];
#pragma unroll
      for (int r = 0; r < 4; ++r)
        a[r] = *(const short8*)&Al[q * 1024 + (64 * wm + 16 * r + l15) * 8];
#pragma unroll
      for (int t = 0; t < 8; ++t) {
        short8 bfr = *(const short8*)&Bl[(8 * wn + t) * 512 + q * 128 + l15 * 8];
#pragma unroll
        for (int r = 0; r < 4; ++r)
          acc[r][t] = __builtin_amdgcn_mfma_f32_16x16x32_bf16(a[r], bfr, acc[r][t], 0, 0, 0);
      }
    }

    // ---- epilogue for chunk ch: cols n' = 256ch + 128wn + 16t + l15,
    //      o = 4ch + 2wn + (t>>2), c = 16(t&3) + l15. ----
    float b2v[8];
#pragma unroll
    for (int t = 0; t < 8; ++t)
      b2v[t] = b2[(16 * (t & 3) + l15) * 64 + 4 * ch + 2 * wn + (t >> 2)];
#pragma unroll
    for (int r = 0; r < 4; ++r) {
#pragma unroll
      for (int i = 0; i < 4; ++i) {
        int plr = 64 * wm + 16 * r + 4 * q + i;
        size_t P = (size_t)bm * 128 + plr;
        float yv[4], mv[4], sv[4];
#pragma unroll
        for (int v = 0; v < 4; ++v) {
          yv[v] = yr[P * 64 + 16 * v + l15];
          mv[v] = mr[P * 64 + 16 * v + l15];
          sv[v] = sr[P * 64 + 16 * v + l15];
        }
#pragma unroll
        for (int u = 0; u < 2; ++u) {
          float ys = 0.f, ms = 0.f, ss = 0.f;
#pragma unroll
          for (int v = 0; v < 4; ++v) {
            float w2f = acc[r][4 * u + v][i] + b2v[4 * u + v];
            float aw  = fabsf(w2f);
            ys += yv[v] * w2f;
            ms += mv[v] * aw;
            ss += sv[v] * aw;
          }
          ys = sum16(ys); ms = sum16(ms); ss = sum16(ss);
          if (l15 == 0) {
            int o = 4 * ch + 2 * wn + u;
            size_t idx = ((size_t)((b << 6) | o) << 14) + (h << 7) + plr;
            out[idx]           = ys;
            out[4194304 + idx] = ms / ss;
            out[8388608 + idx] = 1.0f;
          }
        }
      }
    }
    // reset accumulators for next chunk
#pragma unroll
    for (int r = 0; r < 4; ++r)
#pragma unroll
      for (int t = 0; t < 8; ++t) acc[r][t] = (float4v){0.f, 0.f, 0.f, 0.f};
  }
}

// ---------------------------------------------------------------------------
extern "C" void kernel_launch(void* const* d_in, const int* in_sizes, int n_in,
                              void* d_out, int out_size, void* d_ws, size_t ws_size,
                              hipStream_t stream) {
  const float* x  = (const float*)d_in[0];
  const float* m  = (const float*)d_in[1];
  const float* s  = (const float*)d_in[2];
  const float* W1 = (const float*)d_in[3];
  const float* b1 = (const float*)d_in[4];
  const float* W2 = (const float*)d_in[5];
  const float* b2 = (const float*)d_in[6];
  float* out = (float*)d_out;

  // ws layout (bytes):
  //   feat  bf16 : [0, 150994944)               36*65536*32 elems
  //   W1s   bf16 : [150994944, 152322048)       1152*576
  //   W2s   bf16 : [152322048, 161759232)       1152*4096 (o-major permuted)
  //   yr/mr/sr f32: 3 x 16777216 from 161759232 ; end = 212090880
  if (ws_size < 212090880ull) return;
  char* ws = (char*)d_ws;
  unsigned short* featb = (unsigned short*)ws;
  unsigned short* W1s   = (unsigned short*)(ws + 150994944);
  unsigned short* W2s   = (unsigned short*)(ws + 152322048);
  float* yr = (float*)(ws + 161759232);
  float* mr = (float*)(ws + 178536448);
  float* sr = (float*)(ws + 195313664);

  k_feat<<<294912, 256, 0, stream>>>(x, m, featb);
  k_sw<<<2592, 256, 0, stream>>>(W1, W1s, 576, 36, 663552, 0);
  k_sw<<<18432, 256, 0, stream>>>(W2, W2s, 4096, 256, 4718592, 1);
  dim3 g1(512, 4);
  k_gemm1<<<g1, 512, 0, stream>>>(featb, W1s, b1, x, m, s, yr, mr, sr);
  k_gemm2<<<512, 256, 0, stream>>>(featb, W2s, b2, yr, mr, sr, out);
}